// Round 9
// baseline (347.577 us; speedup 1.0000x reference)
//
#include <hip/hip_runtime.h>
#include <stdint.h>

// Problem constants (from reference)
#define N_CLASSES  10
#define N_TREES    4000
#define DEPTH      6
#define N_INTERNAL 63
#define N_FEATURES 128
#define BATCH      32768
#define LR         0.1f

// Kernel config (R5/R8 skeleton: 32 samples/block, half-wave walks one tree;
// 16 waves/CU; all node traffic on the LDS pipe via DMA-staged tiles).
#define BLOCK       256
#define SAMPLES_PB  32
#define TSPLIT      2
#define SLOTS_PB    (N_TREES / TSPLIT)      // 2000 class-grouped slots per block
#define T_TILE      16                      // trees per LDS tile (8 KB int2 nodes)
#define N_TILES     (SLOTS_PB / T_TILE)     // 125
#define TILES_PER_CLASS 25
#define SUMS_STRIDE 11

// ws layout:
//   [0, 2.048MB)            nodes by slot, interleaved int2 (feat, thr_bits), 64/tree
//   [2.048MB, 3.072MB)      leaves (64 f32/tree), class-grouped slots
//   [3.072MB, 19.85MB)      x^T: [N_FEATURES][BATCH] f32 (DMA-friendly staging)
// slot = (t%10)*400 + t/10.
#define WS_NODES_BYTES  ((size_t)N_TREES * 64 * 8)
#define WS_LEAVES_BYTES ((size_t)N_TREES * 64 * 4)
#define WS_XT_BYTES     ((size_t)N_FEATURES * BATCH * 4)

__global__ void pack_kernel(const int* __restrict__ features,
                            const float* __restrict__ thresholds,
                            const float* __restrict__ leaves,
                            int2* __restrict__ pn, float* __restrict__ pl) {
    int i = blockIdx.x * blockDim.x + threadIdx.x;   // over N_TREES*64
    int t = i >> 6, n = i & 63;
    if (t < N_TREES) {
        int slot = (t % N_CLASSES) * (N_TREES / N_CLASSES) + (t / N_CLASSES);
        if (n < N_INTERNAL)
            pn[slot * 64 + n] = make_int2(features[t * N_INTERNAL + n],
                                          __float_as_int(thresholds[t * N_INTERNAL + n]));
        pl[slot * 64 + n] = leaves[t * 64 + n];
    }
}

// x^T builder: coalesced read of x, scattered dword writes (L2-absorbed, one-off).
__global__ void xt_kernel(const float* __restrict__ x, float* __restrict__ xt) {
    int i = blockIdx.x * blockDim.x + threadIdx.x;   // over BATCH*N_FEATURES
    int s = i >> 7, f = i & 127;
    xt[(size_t)f * BATCH + s] = x[i];
}

__global__ void out_init_kernel(const float* __restrict__ init_out,
                                float* __restrict__ out) {
    int i = blockIdx.x * blockDim.x + threadIdx.x;
    if (i < BATCH * N_CLASSES) {
        int s = i / N_CLASSES;
        out[i] = init_out[i - s * N_CLASSES];
    }
}

// CK-style addrspace casts for global_load_lds (proven R5/R8).
__device__ __forceinline__ void load_lds_16(const void* g, void* l) {
    const auto* g1 = reinterpret_cast<const __attribute__((address_space(1))) uint32_t*>(
        reinterpret_cast<uintptr_t>(g));
    auto* l3 = reinterpret_cast<__attribute__((address_space(3))) uint32_t*>(
        reinterpret_cast<uintptr_t>(l));
    __builtin_amdgcn_global_load_lds(g1, l3, 16, 0, 0);
}

template <bool XT>
__global__ __launch_bounds__(BLOCK, 4) void gbt_eval(
    const float* __restrict__ x,        // original [BATCH][F] (XT=false path)
    const float* __restrict__ xt,       // x^T [F][BATCH]      (XT=true path)
    const int2*  __restrict__ pnodes,   // [N_TREES][64] int2, class-grouped slots
    const float* __restrict__ pleaves,  // [N_TREES][64], class-grouped slots
    float*       __restrict__ out)      // [BATCH][10], pre-init to init_out
{
    __shared__ float xs[N_FEATURES * SAMPLES_PB];       // 16 KB, transposed [f][s]
    __shared__ int2  nbuf[2][T_TILE * 64];              // 2 x 8 KB node tiles
    __shared__ float sums[SAMPLES_PB * SUMS_STRIDE];    // 1.4 KB

    const int tid = threadIdx.x;
    const int sample0 = blockIdx.x * SAMPLES_PB;
    const int slot0   = blockIdx.y * SLOTS_PB;
    const int cls0    = blockIdx.y * (N_CLASSES / TSPLIT);
    const int lane    = tid & 63;
    const int wv      = tid >> 6;       // wave id 0..3

    if (XT) {
        // DMA x^T rows straight into the transposed xs tile: per wave 4 x 1 KB.
        // Lane l covers feature f0+(l>>3), bytes (l&7)*16 of that feature's
        // 128 B sample-chunk; LDS dest = uniform base + l*16 (HW rule).
        #pragma unroll
        for (int q = 0; q < 4; ++q) {
            int f0 = wv * 32 + q * 8;
            const char* g = (const char*)(xt
                + (size_t)(f0 + (lane >> 3)) * BATCH + sample0 + (lane & 7) * 4);
            load_lds_16(g, (char*)xs + (size_t)f0 * SAMPLES_PB * 4);
        }
    } else {
        const float4* xg = (const float4*)(x + (size_t)sample0 * N_FEATURES);
        for (int e = tid; e < SAMPLES_PB * (N_FEATURES / 4); e += BLOCK) {
            int s = e >> 5, f4 = e & 31;
            float4 v = xg[e];
            int f = f4 << 2;
            xs[(f + 0) * SAMPLES_PB + s] = v.x;
            xs[(f + 1) * SAMPLES_PB + s] = v.y;
            xs[(f + 2) * SAMPLES_PB + s] = v.z;
            xs[(f + 3) * SAMPLES_PB + s] = v.w;
        }
    }
    for (int i = tid; i < SAMPLES_PB * SUMS_STRIDE; i += BLOCK) sums[i] = 0.f;

    // Stage one 8 KB int2 node tile: 8 chunks of 1 KB; wave wv DMAs 2 chunks.
    auto stage = [&](int tile, int b) {
        const char* g = (const char*)(pnodes + (size_t)(slot0 + tile * T_TILE) * 64);
        char* lbase = (char*)&nbuf[b][0];
        #pragma unroll
        for (int q = 0; q < 2; ++q) {
            int k = wv * 2 + q;
            load_lds_16(g + k * 1024 + lane * 16, lbase + k * 1024);
        }
    };

    stage(0, 0);
    __syncthreads();   // barrier drains vmcnt: tile 0 + xs DMA visible

    const int sLocal = tid & (SAMPLES_PB - 1);
    const int j      = tid >> 5;        // 0..7 half-wave chunks; trees 2j, 2j+1

    int cur = 0;
    for (int c5 = 0; c5 < N_CLASSES / TSPLIT; ++c5) {
        float acc = 0.f;                // tile is single-class (class-grouped slots)
        for (int t25 = 0; t25 < TILES_PER_CLASS; ++t25) {
            const int tile = c5 * TILES_PER_CLASS + t25;
            if (tile + 1 < N_TILES) stage(tile + 1, cur ^ 1);

            const int2* nb0 = &nbuf[cur][(j * 2 + 0) * 64];
            const int2* nb1 = &nbuf[cur][(j * 2 + 1) * 64];
            int o0 = 0, o1 = 0;
            #pragma unroll
            for (int d = 0; d < DEPTH; ++d) {
                int2 a = nb0[o0];           // ds_read_b64 (interleaved f,thr)
                int2 b = nb1[o1];
                float x0 = xs[a.x * SAMPLES_PB + sLocal];
                float x1 = xs[b.x * SAMPLES_PB + sLocal];
                o0 = 2 * o0 + 1 + (x0 > __int_as_float(a.y) ? 1 : 0);
                o1 = 2 * o1 + 1 + (x1 > __int_as_float(b.y) ? 1 : 0);
            }
            const size_t slotA = (size_t)(slot0 + tile * T_TILE + j * 2);
            acc += pleaves[slotA * 64       + (o0 - N_INTERNAL)];   // L2-resident
            acc += pleaves[(slotA + 1) * 64 + (o1 - N_INTERNAL)];

            __syncthreads();   // nbuf[cur] reads done; prefetch DMA long landed
            cur ^= 1;
        }
        atomicAdd(&sums[sLocal * SUMS_STRIDE + cls0 + c5], acc);
    }
    __syncthreads();

    for (int e = tid; e < SAMPLES_PB * N_CLASSES; e += BLOCK) {
        int s = e / N_CLASSES, k = e - s * N_CLASSES;
        atomicAdd(&out[(size_t)(sample0 + s) * N_CLASSES + k],
                  LR * sums[s * SUMS_STRIDE + k]);
    }
}

// Fallback (ws too small even for nodes+leaves): R3-style direct-global gather.
__global__ __launch_bounds__(BLOCK, 8) void gbt_eval_global(
    const float* __restrict__ x,
    const int*   __restrict__ features,
    const float* __restrict__ thresholds,
    const float* __restrict__ leaf_values,
    float*       __restrict__ out)
{
    __shared__ float xs[N_FEATURES * SAMPLES_PB];
    __shared__ float sums[SAMPLES_PB * N_CLASSES];
    const int tid = threadIdx.x;
    const int sample0 = blockIdx.x * SAMPLES_PB;
    {
        const float4* xg = (const float4*)(x + (size_t)sample0 * N_FEATURES);
        for (int e = tid; e < SAMPLES_PB * (N_FEATURES / 4); e += BLOCK) {
            int s = e >> 5, f4 = e & 31;
            float4 v = xg[e];
            int f = f4 << 2;
            xs[(f + 0) * SAMPLES_PB + s] = v.x;
            xs[(f + 1) * SAMPLES_PB + s] = v.y;
            xs[(f + 2) * SAMPLES_PB + s] = v.z;
            xs[(f + 3) * SAMPLES_PB + s] = v.w;
        }
    }
    for (int i = tid; i < SAMPLES_PB * N_CLASSES; i += BLOCK) sums[i] = 0.f;
    __syncthreads();
    const int sLocal = tid & (SAMPLES_PB - 1);
    const int j = tid >> 5;
    const int TPT = N_TREES / (8 * TSPLIT);
    const int t0 = (blockIdx.y * 8 + j) * TPT;
    float acc[N_CLASSES];
    #pragma unroll
    for (int k = 0; k < N_CLASSES; ++k) acc[k] = 0.f;
    for (int i = 0; i < TPT; i += N_CLASSES) {
        const int tt = t0 + i;
        int idx[N_CLASSES];
        #pragma unroll
        for (int u = 0; u < N_CLASSES; ++u) idx[u] = 0;
        #pragma unroll
        for (int d = 0; d < DEPTH; ++d) {
            #pragma unroll
            for (int u = 0; u < N_CLASSES; ++u) {
                int base = (tt + u) * N_INTERNAL + idx[u];
                float xv = xs[features[base] * SAMPLES_PB + sLocal];
                idx[u] = 2 * idx[u] + 1 + (xv > thresholds[base] ? 1 : 0);
            }
        }
        #pragma unroll
        for (int u = 0; u < N_CLASSES; ++u)
            acc[u] += leaf_values[(size_t)(tt + u) * 64 + idx[u] - N_INTERNAL];
    }
    #pragma unroll
    for (int k = 0; k < N_CLASSES; ++k)
        atomicAdd(&sums[sLocal * N_CLASSES + k], acc[k]);
    __syncthreads();
    for (int e = tid; e < SAMPLES_PB * N_CLASSES; e += BLOCK) {
        int s = e / N_CLASSES, k = e - s * N_CLASSES;
        atomicAdd(&out[(size_t)(sample0 + s) * N_CLASSES + k], LR * sums[e]);
    }
}

extern "C" void kernel_launch(void* const* d_in, const int* in_sizes, int n_in,
                              void* d_out, int out_size, void* d_ws, size_t ws_size,
                              hipStream_t stream) {
    const float* x          = (const float*)d_in[0];
    const int*   features   = (const int*)d_in[1];
    const float* thresholds = (const float*)d_in[2];
    const float* leafvals   = (const float*)d_in[3];
    const float* init_out   = (const float*)d_in[4];
    float*       out        = (float*)d_out;

    {
        int n = BATCH * N_CLASSES;
        out_init_kernel<<<(n + 255) / 256, 256, 0, stream>>>(init_out, out);
    }

    dim3 grid(BATCH / SAMPLES_PB, TSPLIT);  // 1024 x 2

    if (ws_size >= WS_NODES_BYTES + WS_LEAVES_BYTES) {
        int2*  pn = (int2*)d_ws;
        float* pl = (float*)((char*)d_ws + WS_NODES_BYTES);
        int n = N_TREES * 64;
        pack_kernel<<<(n + 255) / 256, 256, 0, stream>>>(features, thresholds,
                                                         leafvals, pn, pl);
        if (ws_size >= WS_NODES_BYTES + WS_LEAVES_BYTES + WS_XT_BYTES) {
            float* xt = (float*)((char*)d_ws + WS_NODES_BYTES + WS_LEAVES_BYTES);
            int m = BATCH * N_FEATURES;
            xt_kernel<<<(m + 255) / 256, 256, 0, stream>>>(x, xt);
            gbt_eval<true><<<grid, BLOCK, 0, stream>>>(x, xt, pn, pl, out);
        } else {
            gbt_eval<false><<<grid, BLOCK, 0, stream>>>(x, nullptr, pn, pl, out);
        }
    } else {
        gbt_eval_global<<<grid, BLOCK, 0, stream>>>(x, features, thresholds,
                                                    leafvals, out);
    }
}

// Round 10
// 324.182 us; speedup vs baseline: 1.0722x; 1.0722x over previous
//
#include <hip/hip_runtime.h>
#include <stdint.h>

// Problem constants (from reference)
#define N_CLASSES  10
#define N_TREES    4000
#define DEPTH      6
#define N_INTERNAL 63
#define N_FEATURES 128
#define BATCH      32768
#define LR         0.1f

// Kernel config (R5/R8 skeleton: 32 samples/block, half-wave walks one tree;
// 16 waves/CU; all node traffic on the LDS pipe via DMA-staged tiles).
#define BLOCK       256
#define SAMPLES_PB  32
#define TSPLIT      2
#define SLOTS_PB    (N_TREES / TSPLIT)      // 2000 class-grouped slots per block
#define T_TILE      16                      // trees per LDS tile (8 KB int2 nodes)
#define N_TILES     (SLOTS_PB / T_TILE)     // 125
#define TILES_PER_CLASS 25
#define SUMS_STRIDE 11

// prep grid split
#define XPOSE_BLOCKS (BATCH / SAMPLES_PB)           // 1024
#define PACK_BLOCKS  ((N_TREES * 64) / BLOCK)       // 1000

// ws layout:
//   [0, 2.048MB)        nodes by slot, interleaved int2 (feat, thr_bits), 64/tree
//   [2.048MB, 3.072MB)  leaves (64 f32/tree), class-grouped slots
//   [3.072MB, 19.85MB)  x^T: [N_FEATURES][BATCH] f32 (DMA-friendly staging)
// slot = (t%10)*400 + t/10.
#define WS_NODES_BYTES  ((size_t)N_TREES * 64 * 8)
#define WS_LEAVES_BYTES ((size_t)N_TREES * 64 * 4)
#define WS_XT_BYTES     ((size_t)N_FEATURES * BATCH * 4)

// Fused prep: blocks [0,1024) transpose x into x^T (LDS-tiled, coalesced both
// sides); blocks [1024,2024) pack nodes+leaves into class-grouped slots.
__global__ void prep_kernel(const float* __restrict__ x,
                            const int* __restrict__ features,
                            const float* __restrict__ thresholds,
                            const float* __restrict__ leaves,
                            int2* __restrict__ pn, float* __restrict__ pl,
                            float* __restrict__ xt) {
    const int tid = threadIdx.x;
    if (blockIdx.x < XPOSE_BLOCKS) {
        __shared__ float tile[N_FEATURES * 33];     // stride 33: cheap LDS phases
        const int sample0 = blockIdx.x * SAMPLES_PB;
        const float4* xg = (const float4*)(x + (size_t)sample0 * N_FEATURES);
        #pragma unroll
        for (int k = 0; k < 4; ++k) {
            int e = tid + k * BLOCK;
            int s = e >> 5, f4 = e & 31;
            float4 v = xg[e];
            int f = f4 << 2;
            tile[(f + 0) * 33 + s] = v.x;
            tile[(f + 1) * 33 + s] = v.y;
            tile[(f + 2) * 33 + s] = v.z;
            tile[(f + 3) * 33 + s] = v.w;
        }
        __syncthreads();
        #pragma unroll
        for (int k = 0; k < 4; ++k) {
            int e = tid + k * BLOCK;
            int f = e >> 3, sq = e & 7;             // 128 f x 8 sample-quads
            float4 w;
            w.x = tile[f * 33 + 4 * sq + 0];
            w.y = tile[f * 33 + 4 * sq + 1];
            w.z = tile[f * 33 + 4 * sq + 2];
            w.w = tile[f * 33 + 4 * sq + 3];
            *(float4*)(xt + (size_t)f * BATCH + sample0 + 4 * sq) = w;  // coalesced
        }
    } else {
        int i = (blockIdx.x - XPOSE_BLOCKS) * BLOCK + tid;  // over N_TREES*64
        int t = i >> 6, n = i & 63;
        int slot = (t % N_CLASSES) * (N_TREES / N_CLASSES) + (t / N_CLASSES);
        if (n < N_INTERNAL)
            pn[slot * 64 + n] = make_int2(features[t * N_INTERNAL + n],
                                          __float_as_int(thresholds[t * N_INTERNAL + n]));
        pl[slot * 64 + n] = leaves[t * 64 + n];
    }
}

// Standalone pack (mid/fallback tiers without xt space)
__global__ void pack_kernel(const int* __restrict__ features,
                            const float* __restrict__ thresholds,
                            const float* __restrict__ leaves,
                            int2* __restrict__ pn, float* __restrict__ pl) {
    int i = blockIdx.x * blockDim.x + threadIdx.x;
    int t = i >> 6, n = i & 63;
    if (t < N_TREES) {
        int slot = (t % N_CLASSES) * (N_TREES / N_CLASSES) + (t / N_CLASSES);
        if (n < N_INTERNAL)
            pn[slot * 64 + n] = make_int2(features[t * N_INTERNAL + n],
                                          __float_as_int(thresholds[t * N_INTERNAL + n]));
        pl[slot * 64 + n] = leaves[t * 64 + n];
    }
}

// CK-style addrspace casts for global_load_lds (proven R5/R8/R9).
__device__ __forceinline__ void load_lds_16(const void* g, void* l) {
    const auto* g1 = reinterpret_cast<const __attribute__((address_space(1))) uint32_t*>(
        reinterpret_cast<uintptr_t>(g));
    auto* l3 = reinterpret_cast<__attribute__((address_space(3))) uint32_t*>(
        reinterpret_cast<uintptr_t>(l));
    __builtin_amdgcn_global_load_lds(g1, l3, 16, 0, 0);
}

template <bool XT>
__global__ __launch_bounds__(BLOCK, 4) void gbt_eval(
    const float* __restrict__ x,        // original [BATCH][F] (XT=false path)
    const float* __restrict__ xt,       // x^T [F][BATCH]      (XT=true path)
    const int2*  __restrict__ pnodes,   // [N_TREES][64] int2, class-grouped slots
    const float* __restrict__ pleaves,  // [N_TREES][64], class-grouped slots
    const float* __restrict__ init_out, // [10]
    float*       __restrict__ out)      // [BATCH][10], zeroed by memsetAsync
{
    __shared__ float xs[N_FEATURES * SAMPLES_PB];       // 16 KB, transposed [f][s]
    __shared__ int2  nbuf[2][T_TILE * 64];              // 2 x 8 KB node tiles
    __shared__ float sums[SAMPLES_PB * SUMS_STRIDE];    // 1.4 KB

    const int tid = threadIdx.x;
    const int sample0 = blockIdx.x * SAMPLES_PB;
    const int slot0   = blockIdx.y * SLOTS_PB;
    const int cls0    = blockIdx.y * (N_CLASSES / TSPLIT);
    const int lane    = tid & 63;
    const int wv      = tid >> 6;       // wave id 0..3

    if (XT) {
        // DMA x^T rows straight into the transposed xs tile: per wave 4 x 1 KB.
        #pragma unroll
        for (int q = 0; q < 4; ++q) {
            int f0 = wv * 32 + q * 8;
            const char* g = (const char*)(xt
                + (size_t)(f0 + (lane >> 3)) * BATCH + sample0 + (lane & 7) * 4);
            load_lds_16(g, (char*)xs + (size_t)f0 * SAMPLES_PB * 4);
        }
    } else {
        const float4* xg = (const float4*)(x + (size_t)sample0 * N_FEATURES);
        for (int e = tid; e < SAMPLES_PB * (N_FEATURES / 4); e += BLOCK) {
            int s = e >> 5, f4 = e & 31;
            float4 v = xg[e];
            int f = f4 << 2;
            xs[(f + 0) * SAMPLES_PB + s] = v.x;
            xs[(f + 1) * SAMPLES_PB + s] = v.y;
            xs[(f + 2) * SAMPLES_PB + s] = v.z;
            xs[(f + 3) * SAMPLES_PB + s] = v.w;
        }
    }
    for (int i = tid; i < SAMPLES_PB * SUMS_STRIDE; i += BLOCK) sums[i] = 0.f;

    // Stage one 8 KB int2 node tile: 8 chunks of 1 KB; wave wv DMAs 2 chunks.
    auto stage = [&](int tile, int b) {
        const char* g = (const char*)(pnodes + (size_t)(slot0 + tile * T_TILE) * 64);
        char* lbase = (char*)&nbuf[b][0];
        #pragma unroll
        for (int q = 0; q < 2; ++q) {
            int k = wv * 2 + q;
            load_lds_16(g + k * 1024 + lane * 16, lbase + k * 1024);
        }
    };

    stage(0, 0);
    __syncthreads();   // barrier drains vmcnt: tile 0 + xs DMA visible

    const int sLocal = tid & (SAMPLES_PB - 1);
    const int j      = tid >> 5;        // 0..7 half-wave chunks; trees 2j, 2j+1

    int cur = 0;
    for (int c5 = 0; c5 < N_CLASSES / TSPLIT; ++c5) {
        float acc = 0.f;                // tile is single-class (class-grouped slots)
        for (int t25 = 0; t25 < TILES_PER_CLASS; ++t25) {
            const int tile = c5 * TILES_PER_CLASS + t25;
            if (tile + 1 < N_TILES) stage(tile + 1, cur ^ 1);

            const int2* nb0 = &nbuf[cur][(j * 2 + 0) * 64];
            const int2* nb1 = &nbuf[cur][(j * 2 + 1) * 64];
            int o0 = 0, o1 = 0;
            #pragma unroll
            for (int d = 0; d < DEPTH; ++d) {
                int2 a = nb0[o0];           // ds_read_b64 (interleaved f,thr)
                int2 b = nb1[o1];
                float x0 = xs[a.x * SAMPLES_PB + sLocal];
                float x1 = xs[b.x * SAMPLES_PB + sLocal];
                o0 = 2 * o0 + 1 + (x0 > __int_as_float(a.y) ? 1 : 0);
                o1 = 2 * o1 + 1 + (x1 > __int_as_float(b.y) ? 1 : 0);
            }
            const size_t slotA = (size_t)(slot0 + tile * T_TILE + j * 2);
            acc += pleaves[slotA * 64       + (o0 - N_INTERNAL)];   // L2-resident
            acc += pleaves[(slotA + 1) * 64 + (o1 - N_INTERNAL)];

            __syncthreads();   // nbuf[cur] reads done; prefetch DMA long landed
            cur ^= 1;
        }
        atomicAdd(&sums[sLocal * SUMS_STRIDE + cls0 + c5], acc);
    }
    __syncthreads();

    // out was zeroed; y==0 blocks fold in init_out. 2 atomic contributors/elem.
    for (int e = tid; e < SAMPLES_PB * N_CLASSES; e += BLOCK) {
        int s = e / N_CLASSES, k = e - s * N_CLASSES;
        float v = LR * sums[s * SUMS_STRIDE + k];
        if (blockIdx.y == 0) v += init_out[k];
        atomicAdd(&out[(size_t)(sample0 + s) * N_CLASSES + k], v);
    }
}

// Fallback (ws too small even for nodes+leaves): R3-style direct-global gather.
__global__ __launch_bounds__(BLOCK, 8) void gbt_eval_global(
    const float* __restrict__ x,
    const int*   __restrict__ features,
    const float* __restrict__ thresholds,
    const float* __restrict__ leaf_values,
    const float* __restrict__ init_out,
    float*       __restrict__ out)
{
    __shared__ float xs[N_FEATURES * SAMPLES_PB];
    __shared__ float sums[SAMPLES_PB * N_CLASSES];
    const int tid = threadIdx.x;
    const int sample0 = blockIdx.x * SAMPLES_PB;
    {
        const float4* xg = (const float4*)(x + (size_t)sample0 * N_FEATURES);
        for (int e = tid; e < SAMPLES_PB * (N_FEATURES / 4); e += BLOCK) {
            int s = e >> 5, f4 = e & 31;
            float4 v = xg[e];
            int f = f4 << 2;
            xs[(f + 0) * SAMPLES_PB + s] = v.x;
            xs[(f + 1) * SAMPLES_PB + s] = v.y;
            xs[(f + 2) * SAMPLES_PB + s] = v.z;
            xs[(f + 3) * SAMPLES_PB + s] = v.w;
        }
    }
    for (int i = tid; i < SAMPLES_PB * N_CLASSES; i += BLOCK) sums[i] = 0.f;
    __syncthreads();
    const int sLocal = tid & (SAMPLES_PB - 1);
    const int j = tid >> 5;
    const int TPT = N_TREES / (8 * TSPLIT);
    const int t0 = (blockIdx.y * 8 + j) * TPT;
    float acc[N_CLASSES];
    #pragma unroll
    for (int k = 0; k < N_CLASSES; ++k) acc[k] = 0.f;
    for (int i = 0; i < TPT; i += N_CLASSES) {
        const int tt = t0 + i;
        int idx[N_CLASSES];
        #pragma unroll
        for (int u = 0; u < N_CLASSES; ++u) idx[u] = 0;
        #pragma unroll
        for (int d = 0; d < DEPTH; ++d) {
            #pragma unroll
            for (int u = 0; u < N_CLASSES; ++u) {
                int base = (tt + u) * N_INTERNAL + idx[u];
                float xv = xs[features[base] * SAMPLES_PB + sLocal];
                idx[u] = 2 * idx[u] + 1 + (xv > thresholds[base] ? 1 : 0);
            }
        }
        #pragma unroll
        for (int u = 0; u < N_CLASSES; ++u)
            acc[u] += leaf_values[(size_t)(tt + u) * 64 + idx[u] - N_INTERNAL];
    }
    #pragma unroll
    for (int k = 0; k < N_CLASSES; ++k)
        atomicAdd(&sums[sLocal * N_CLASSES + k], acc[k]);
    __syncthreads();
    for (int e = tid; e < SAMPLES_PB * N_CLASSES; e += BLOCK) {
        int s = e / N_CLASSES, k = e - s * N_CLASSES;
        float v = LR * sums[e];
        if (blockIdx.y == 0) v += init_out[k];
        atomicAdd(&out[(size_t)(sample0 + s) * N_CLASSES + k], v);
    }
}

extern "C" void kernel_launch(void* const* d_in, const int* in_sizes, int n_in,
                              void* d_out, int out_size, void* d_ws, size_t ws_size,
                              hipStream_t stream) {
    const float* x          = (const float*)d_in[0];
    const int*   features   = (const int*)d_in[1];
    const float* thresholds = (const float*)d_in[2];
    const float* leafvals   = (const float*)d_in[3];
    const float* init_out   = (const float*)d_in[4];
    float*       out        = (float*)d_out;

    hipMemsetAsync(out, 0, (size_t)out_size * sizeof(float), stream);

    dim3 grid(BATCH / SAMPLES_PB, TSPLIT);  // 1024 x 2

    if (ws_size >= WS_NODES_BYTES + WS_LEAVES_BYTES + WS_XT_BYTES) {
        int2*  pn = (int2*)d_ws;
        float* pl = (float*)((char*)d_ws + WS_NODES_BYTES);
        float* xt = (float*)((char*)d_ws + WS_NODES_BYTES + WS_LEAVES_BYTES);
        prep_kernel<<<XPOSE_BLOCKS + PACK_BLOCKS, BLOCK, 0, stream>>>(
            x, features, thresholds, leafvals, pn, pl, xt);
        gbt_eval<true><<<grid, BLOCK, 0, stream>>>(x, xt, pn, pl, init_out, out);
    } else if (ws_size >= WS_NODES_BYTES + WS_LEAVES_BYTES) {
        int2*  pn = (int2*)d_ws;
        float* pl = (float*)((char*)d_ws + WS_NODES_BYTES);
        int n = N_TREES * 64;
        pack_kernel<<<(n + 255) / 256, 256, 0, stream>>>(features, thresholds,
                                                         leafvals, pn, pl);
        gbt_eval<false><<<grid, BLOCK, 0, stream>>>(x, nullptr, pn, pl, init_out, out);
    } else {
        gbt_eval_global<<<grid, BLOCK, 0, stream>>>(x, features, thresholds,
                                                    leafvals, init_out, out);
    }
}

// Round 11
// 321.856 us; speedup vs baseline: 1.0799x; 1.0072x over previous
//
#include <hip/hip_runtime.h>
#include <stdint.h>

// Problem constants (from reference)
#define N_CLASSES  10
#define N_TREES    4000
#define DEPTH      6
#define N_INTERNAL 63
#define N_FEATURES 128
#define BATCH      32768
#define LR         0.1f

// Kernel config (R5/R8 skeleton; TSPLIT=1: each block owns ALL trees for its
// 32 samples -> grid 1024 = exactly 4 blocks/CU x 256 CU, one residency round,
// no output atomics, no memset).
#define BLOCK       256
#define SAMPLES_PB  32
#define T_TILE      16                      // trees per LDS tile (8 KB int2 nodes)
#define N_TILES     (N_TREES / T_TILE)      // 250
#define TILES_PER_CLASS ((N_TREES / N_CLASSES) / T_TILE)   // 25
#define SUMS_STRIDE 11

// prep grid split
#define XPOSE_BLOCKS (BATCH / SAMPLES_PB)           // 1024
#define PACK_BLOCKS  ((N_TREES * 64) / BLOCK)       // 1000

// ws layout:
//   [0, 2.048MB)        nodes by slot, interleaved int2 (feat, thr_bits), 64/tree
//   [2.048MB, 3.072MB)  leaves (64 f32/tree), class-grouped slots
//   [3.072MB, 19.85MB)  x^T: [N_FEATURES][BATCH] f32 (DMA-friendly staging)
// slot = (t%10)*400 + t/10  (class-grouped: 25-tile runs are single-class).
#define WS_NODES_BYTES  ((size_t)N_TREES * 64 * 8)
#define WS_LEAVES_BYTES ((size_t)N_TREES * 64 * 4)
#define WS_XT_BYTES     ((size_t)N_FEATURES * BATCH * 4)

// Fused prep: blocks [0,1024) transpose x into x^T (LDS-tiled, coalesced both
// sides); blocks [1024,2024) pack nodes+leaves into class-grouped slots.
__global__ void prep_kernel(const float* __restrict__ x,
                            const int* __restrict__ features,
                            const float* __restrict__ thresholds,
                            const float* __restrict__ leaves,
                            int2* __restrict__ pn, float* __restrict__ pl,
                            float* __restrict__ xt) {
    const int tid = threadIdx.x;
    if (blockIdx.x < XPOSE_BLOCKS) {
        __shared__ float tile[N_FEATURES * 33];     // stride 33: cheap LDS phases
        const int sample0 = blockIdx.x * SAMPLES_PB;
        const float4* xg = (const float4*)(x + (size_t)sample0 * N_FEATURES);
        #pragma unroll
        for (int k = 0; k < 4; ++k) {
            int e = tid + k * BLOCK;
            int s = e >> 5, f4 = e & 31;
            float4 v = xg[e];
            int f = f4 << 2;
            tile[(f + 0) * 33 + s] = v.x;
            tile[(f + 1) * 33 + s] = v.y;
            tile[(f + 2) * 33 + s] = v.z;
            tile[(f + 3) * 33 + s] = v.w;
        }
        __syncthreads();
        #pragma unroll
        for (int k = 0; k < 4; ++k) {
            int e = tid + k * BLOCK;
            int f = e >> 3, sq = e & 7;             // 128 f x 8 sample-quads
            float4 w;
            w.x = tile[f * 33 + 4 * sq + 0];
            w.y = tile[f * 33 + 4 * sq + 1];
            w.z = tile[f * 33 + 4 * sq + 2];
            w.w = tile[f * 33 + 4 * sq + 3];
            *(float4*)(xt + (size_t)f * BATCH + sample0 + 4 * sq) = w;  // coalesced
        }
    } else {
        int i = (blockIdx.x - XPOSE_BLOCKS) * BLOCK + tid;  // over N_TREES*64
        int t = i >> 6, n = i & 63;
        int slot = (t % N_CLASSES) * (N_TREES / N_CLASSES) + (t / N_CLASSES);
        if (n < N_INTERNAL)
            pn[slot * 64 + n] = make_int2(features[t * N_INTERNAL + n],
                                          __float_as_int(thresholds[t * N_INTERNAL + n]));
        pl[slot * 64 + n] = leaves[t * 64 + n];
    }
}

// Standalone pack (mid tier without xt space)
__global__ void pack_kernel(const int* __restrict__ features,
                            const float* __restrict__ thresholds,
                            const float* __restrict__ leaves,
                            int2* __restrict__ pn, float* __restrict__ pl) {
    int i = blockIdx.x * blockDim.x + threadIdx.x;
    int t = i >> 6, n = i & 63;
    if (t < N_TREES) {
        int slot = (t % N_CLASSES) * (N_TREES / N_CLASSES) + (t / N_CLASSES);
        if (n < N_INTERNAL)
            pn[slot * 64 + n] = make_int2(features[t * N_INTERNAL + n],
                                          __float_as_int(thresholds[t * N_INTERNAL + n]));
        pl[slot * 64 + n] = leaves[t * 64 + n];
    }
}

// CK-style addrspace casts for global_load_lds (proven R5/R8/R9/R10).
__device__ __forceinline__ void load_lds_16(const void* g, void* l) {
    const auto* g1 = reinterpret_cast<const __attribute__((address_space(1))) uint32_t*>(
        reinterpret_cast<uintptr_t>(g));
    auto* l3 = reinterpret_cast<__attribute__((address_space(3))) uint32_t*>(
        reinterpret_cast<uintptr_t>(l));
    __builtin_amdgcn_global_load_lds(g1, l3, 16, 0, 0);
}

template <bool XT>
__global__ __launch_bounds__(BLOCK, 4) void gbt_eval(
    const float* __restrict__ x,        // original [BATCH][F] (XT=false path)
    const float* __restrict__ xt,       // x^T [F][BATCH]      (XT=true path)
    const int2*  __restrict__ pnodes,   // [N_TREES][64] int2, class-grouped slots
    const float* __restrict__ pleaves,  // [N_TREES][64], class-grouped slots
    const float* __restrict__ init_out, // [10]
    float*       __restrict__ out)      // [BATCH][10], written directly
{
    __shared__ float xs[N_FEATURES * SAMPLES_PB];       // 16 KB, transposed [f][s]
    __shared__ int2  nbuf[2][T_TILE * 64];              // 2 x 8 KB node tiles
    __shared__ float sums[SAMPLES_PB * SUMS_STRIDE];    // 1.4 KB

    const int tid = threadIdx.x;
    const int sample0 = blockIdx.x * SAMPLES_PB;
    const int lane    = tid & 63;
    const int wv      = tid >> 6;       // wave id 0..3

    if (XT) {
        // DMA x^T rows straight into the transposed xs tile: per wave 4 x 1 KB.
        #pragma unroll
        for (int q = 0; q < 4; ++q) {
            int f0 = wv * 32 + q * 8;
            const char* g = (const char*)(xt
                + (size_t)(f0 + (lane >> 3)) * BATCH + sample0 + (lane & 7) * 4);
            load_lds_16(g, (char*)xs + (size_t)f0 * SAMPLES_PB * 4);
        }
    } else {
        const float4* xg = (const float4*)(x + (size_t)sample0 * N_FEATURES);
        for (int e = tid; e < SAMPLES_PB * (N_FEATURES / 4); e += BLOCK) {
            int s = e >> 5, f4 = e & 31;
            float4 v = xg[e];
            int f = f4 << 2;
            xs[(f + 0) * SAMPLES_PB + s] = v.x;
            xs[(f + 1) * SAMPLES_PB + s] = v.y;
            xs[(f + 2) * SAMPLES_PB + s] = v.z;
            xs[(f + 3) * SAMPLES_PB + s] = v.w;
        }
    }
    for (int i = tid; i < SAMPLES_PB * SUMS_STRIDE; i += BLOCK) sums[i] = 0.f;

    // Stage one 8 KB int2 node tile: 8 chunks of 1 KB; wave wv DMAs 2 chunks.
    auto stage = [&](int tile, int b) {
        const char* g = (const char*)(pnodes + (size_t)(tile * T_TILE) * 64);
        char* lbase = (char*)&nbuf[b][0];
        #pragma unroll
        for (int q = 0; q < 2; ++q) {
            int k = wv * 2 + q;
            load_lds_16(g + k * 1024 + lane * 16, lbase + k * 1024);
        }
    };

    stage(0, 0);
    __syncthreads();   // barrier drains vmcnt: tile 0 + xs DMA visible

    const int sLocal = tid & (SAMPLES_PB - 1);
    const int j      = tid >> 5;        // 0..7 half-wave chunks; trees 2j, 2j+1

    int cur = 0;
    for (int c = 0; c < N_CLASSES; ++c) {
        float acc = 0.f;                // 25-tile span is single-class
        for (int t25 = 0; t25 < TILES_PER_CLASS; ++t25) {
            const int tile = c * TILES_PER_CLASS + t25;
            if (tile + 1 < N_TILES) stage(tile + 1, cur ^ 1);

            const int2* nb0 = &nbuf[cur][(j * 2 + 0) * 64];
            const int2* nb1 = &nbuf[cur][(j * 2 + 1) * 64];
            int o0 = 0, o1 = 0;
            #pragma unroll
            for (int d = 0; d < DEPTH; ++d) {
                int2 a = nb0[o0];           // ds_read_b64 (interleaved f,thr)
                int2 b = nb1[o1];
                float x0 = xs[a.x * SAMPLES_PB + sLocal];
                float x1 = xs[b.x * SAMPLES_PB + sLocal];
                o0 = 2 * o0 + 1 + (x0 > __int_as_float(a.y) ? 1 : 0);
                o1 = 2 * o1 + 1 + (x1 > __int_as_float(b.y) ? 1 : 0);
            }
            const size_t slotA = (size_t)(tile * T_TILE + j * 2);
            acc += pleaves[slotA * 64       + (o0 - N_INTERNAL)];   // L2-resident
            acc += pleaves[(slotA + 1) * 64 + (o1 - N_INTERNAL)];

            __syncthreads();   // nbuf[cur] reads done; prefetch DMA long landed
            cur ^= 1;
        }
        atomicAdd(&sums[sLocal * SUMS_STRIDE + c], acc);
    }
    __syncthreads();

    // Sole owner of these samples: plain coalesced stores, init folded in.
    for (int e = tid; e < SAMPLES_PB * N_CLASSES; e += BLOCK) {
        int s = e / N_CLASSES, k = e - s * N_CLASSES;
        out[(size_t)(sample0 + s) * N_CLASSES + k] =
            init_out[k] + LR * sums[s * SUMS_STRIDE + k];
    }
}

// Fallback (ws too small even for nodes+leaves): direct-global gather,
// single block per 32 samples owns all trees (no atomics on out).
__global__ __launch_bounds__(BLOCK, 8) void gbt_eval_global(
    const float* __restrict__ x,
    const int*   __restrict__ features,
    const float* __restrict__ thresholds,
    const float* __restrict__ leaf_values,
    const float* __restrict__ init_out,
    float*       __restrict__ out)
{
    __shared__ float xs[N_FEATURES * SAMPLES_PB];
    __shared__ float sums[SAMPLES_PB * N_CLASSES];
    const int tid = threadIdx.x;
    const int sample0 = blockIdx.x * SAMPLES_PB;
    {
        const float4* xg = (const float4*)(x + (size_t)sample0 * N_FEATURES);
        for (int e = tid; e < SAMPLES_PB * (N_FEATURES / 4); e += BLOCK) {
            int s = e >> 5, f4 = e & 31;
            float4 v = xg[e];
            int f = f4 << 2;
            xs[(f + 0) * SAMPLES_PB + s] = v.x;
            xs[(f + 1) * SAMPLES_PB + s] = v.y;
            xs[(f + 2) * SAMPLES_PB + s] = v.z;
            xs[(f + 3) * SAMPLES_PB + s] = v.w;
        }
    }
    for (int i = tid; i < SAMPLES_PB * N_CLASSES; i += BLOCK) sums[i] = 0.f;
    __syncthreads();
    const int sLocal = tid & (SAMPLES_PB - 1);
    const int j = tid >> 5;
    const int TPT = N_TREES / 8;        // 500 trees per half-wave chunk
    const int t0 = j * TPT;
    float acc[N_CLASSES];
    #pragma unroll
    for (int k = 0; k < N_CLASSES; ++k) acc[k] = 0.f;
    for (int i = 0; i < TPT; i += N_CLASSES) {
        const int tt = t0 + i;
        int idx[N_CLASSES];
        #pragma unroll
        for (int u = 0; u < N_CLASSES; ++u) idx[u] = 0;
        #pragma unroll
        for (int d = 0; d < DEPTH; ++d) {
            #pragma unroll
            for (int u = 0; u < N_CLASSES; ++u) {
                int base = (tt + u) * N_INTERNAL + idx[u];
                float xv = xs[features[base] * SAMPLES_PB + sLocal];
                idx[u] = 2 * idx[u] + 1 + (xv > thresholds[base] ? 1 : 0);
            }
        }
        #pragma unroll
        for (int u = 0; u < N_CLASSES; ++u)
            acc[u] += leaf_values[(size_t)(tt + u) * 64 + idx[u] - N_INTERNAL];
    }
    #pragma unroll
    for (int k = 0; k < N_CLASSES; ++k)
        atomicAdd(&sums[sLocal * N_CLASSES + k], acc[k]);
    __syncthreads();
    for (int e = tid; e < SAMPLES_PB * N_CLASSES; e += BLOCK) {
        int s = e / N_CLASSES, k = e - s * N_CLASSES;
        out[(size_t)(sample0 + s) * N_CLASSES + k] = init_out[k] + LR * sums[e];
    }
}

extern "C" void kernel_launch(void* const* d_in, const int* in_sizes, int n_in,
                              void* d_out, int out_size, void* d_ws, size_t ws_size,
                              hipStream_t stream) {
    const float* x          = (const float*)d_in[0];
    const int*   features   = (const int*)d_in[1];
    const float* thresholds = (const float*)d_in[2];
    const float* leafvals   = (const float*)d_in[3];
    const float* init_out   = (const float*)d_in[4];
    float*       out        = (float*)d_out;

    const int grid = BATCH / SAMPLES_PB;    // 1024 = 256 CU x 4 blocks

    if (ws_size >= WS_NODES_BYTES + WS_LEAVES_BYTES + WS_XT_BYTES) {
        int2*  pn = (int2*)d_ws;
        float* pl = (float*)((char*)d_ws + WS_NODES_BYTES);
        float* xt = (float*)((char*)d_ws + WS_NODES_BYTES + WS_LEAVES_BYTES);
        prep_kernel<<<XPOSE_BLOCKS + PACK_BLOCKS, BLOCK, 0, stream>>>(
            x, features, thresholds, leafvals, pn, pl, xt);
        gbt_eval<true><<<grid, BLOCK, 0, stream>>>(x, xt, pn, pl, init_out, out);
    } else if (ws_size >= WS_NODES_BYTES + WS_LEAVES_BYTES) {
        int2*  pn = (int2*)d_ws;
        float* pl = (float*)((char*)d_ws + WS_NODES_BYTES);
        int n = N_TREES * 64;
        pack_kernel<<<(n + 255) / 256, 256, 0, stream>>>(features, thresholds,
                                                         leafvals, pn, pl);
        gbt_eval<false><<<grid, BLOCK, 0, stream>>>(x, nullptr, pn, pl, init_out, out);
    } else {
        gbt_eval_global<<<grid, BLOCK, 0, stream>>>(x, features, thresholds,
                                                    leafvals, init_out, out);
    }
}

// Round 12
// 315.144 us; speedup vs baseline: 1.1029x; 1.0213x over previous
//
#include <hip/hip_runtime.h>
#include <stdint.h>

// Problem constants (from reference)
#define N_CLASSES  10
#define N_TREES    4000
#define DEPTH      6
#define N_INTERNAL 63
#define N_FEATURES 128
#define BATCH      32768
#define LR         0.1f

// Kernel config (R5/R8 skeleton; TSPLIT=1: each block owns ALL trees for its
// 32 samples -> grid 1024 = exactly 4 blocks/CU x 256 CU, one residency round,
// no output atomics, no memset). R12: per-tile __syncthreads removed -- tile
// buffers are WAVE-PRIVATE (wave wv DMAs trees 4wv..4wv+3; its half-waves
// j=2wv,2wv+1 read exactly those trees), so only wave-local vmcnt ordering
// is needed (FIFO: leaf-load consumption drains the older DMA pair).
#define BLOCK       256
#define SAMPLES_PB  32
#define T_TILE      16                      // trees per LDS tile (8 KB int2 nodes)
#define N_TILES     (N_TREES / T_TILE)      // 250
#define TILES_PER_CLASS ((N_TREES / N_CLASSES) / T_TILE)   // 25
#define SUMS_STRIDE 11

// prep grid split
#define XPOSE_BLOCKS (BATCH / SAMPLES_PB)           // 1024
#define PACK_BLOCKS  ((N_TREES * 64) / BLOCK)       // 1000

// ws layout:
//   [0, 2.048MB)        nodes by slot, interleaved int2 (feat, thr_bits), 64/tree
//   [2.048MB, 3.072MB)  leaves (64 f32/tree), class-grouped slots
//   [3.072MB, 19.85MB)  x^T: [N_FEATURES][BATCH] f32 (DMA-friendly staging)
// slot = (t%10)*400 + t/10  (class-grouped: 25-tile runs are single-class).
#define WS_NODES_BYTES  ((size_t)N_TREES * 64 * 8)
#define WS_LEAVES_BYTES ((size_t)N_TREES * 64 * 4)
#define WS_XT_BYTES     ((size_t)N_FEATURES * BATCH * 4)

// s_waitcnt immediates (gfx9 encoding): vmcnt[3:0] | expcnt<<4 | lgkmcnt<<8
#define WAITCNT_VM2  0x0F72    // vmcnt(2): wait for all but the 2 newest VMEM ops
#define WAITCNT_VM0  0x0F70    // vmcnt(0)

// Fused prep: blocks [0,1024) transpose x into x^T (LDS-tiled, coalesced both
// sides); blocks [1024,2024) pack nodes+leaves into class-grouped slots.
__global__ void prep_kernel(const float* __restrict__ x,
                            const int* __restrict__ features,
                            const float* __restrict__ thresholds,
                            const float* __restrict__ leaves,
                            int2* __restrict__ pn, float* __restrict__ pl,
                            float* __restrict__ xt) {
    const int tid = threadIdx.x;
    if (blockIdx.x < XPOSE_BLOCKS) {
        __shared__ float tile[N_FEATURES * 33];     // stride 33: cheap LDS phases
        const int sample0 = blockIdx.x * SAMPLES_PB;
        const float4* xg = (const float4*)(x + (size_t)sample0 * N_FEATURES);
        #pragma unroll
        for (int k = 0; k < 4; ++k) {
            int e = tid + k * BLOCK;
            int s = e >> 5, f4 = e & 31;
            float4 v = xg[e];
            int f = f4 << 2;
            tile[(f + 0) * 33 + s] = v.x;
            tile[(f + 1) * 33 + s] = v.y;
            tile[(f + 2) * 33 + s] = v.z;
            tile[(f + 3) * 33 + s] = v.w;
        }
        __syncthreads();
        #pragma unroll
        for (int k = 0; k < 4; ++k) {
            int e = tid + k * BLOCK;
            int f = e >> 3, sq = e & 7;             // 128 f x 8 sample-quads
            float4 w;
            w.x = tile[f * 33 + 4 * sq + 0];
            w.y = tile[f * 33 + 4 * sq + 1];
            w.z = tile[f * 33 + 4 * sq + 2];
            w.w = tile[f * 33 + 4 * sq + 3];
            *(float4*)(xt + (size_t)f * BATCH + sample0 + 4 * sq) = w;  // coalesced
        }
    } else {
        int i = (blockIdx.x - XPOSE_BLOCKS) * BLOCK + tid;  // over N_TREES*64
        int t = i >> 6, n = i & 63;
        int slot = (t % N_CLASSES) * (N_TREES / N_CLASSES) + (t / N_CLASSES);
        if (n < N_INTERNAL)
            pn[slot * 64 + n] = make_int2(features[t * N_INTERNAL + n],
                                          __float_as_int(thresholds[t * N_INTERNAL + n]));
        pl[slot * 64 + n] = leaves[t * 64 + n];
    }
}

// Standalone pack (mid tier without xt space)
__global__ void pack_kernel(const int* __restrict__ features,
                            const float* __restrict__ thresholds,
                            const float* __restrict__ leaves,
                            int2* __restrict__ pn, float* __restrict__ pl) {
    int i = blockIdx.x * blockDim.x + threadIdx.x;
    int t = i >> 6, n = i & 63;
    if (t < N_TREES) {
        int slot = (t % N_CLASSES) * (N_TREES / N_CLASSES) + (t / N_CLASSES);
        if (n < N_INTERNAL)
            pn[slot * 64 + n] = make_int2(features[t * N_INTERNAL + n],
                                          __float_as_int(thresholds[t * N_INTERNAL + n]));
        pl[slot * 64 + n] = leaves[t * 64 + n];
    }
}

// CK-style addrspace casts for global_load_lds (proven R5..R11).
__device__ __forceinline__ void load_lds_16(const void* g, void* l) {
    const auto* g1 = reinterpret_cast<const __attribute__((address_space(1))) uint32_t*>(
        reinterpret_cast<uintptr_t>(g));
    auto* l3 = reinterpret_cast<__attribute__((address_space(3))) uint32_t*>(
        reinterpret_cast<uintptr_t>(l));
    __builtin_amdgcn_global_load_lds(g1, l3, 16, 0, 0);
}

template <bool XT>
__global__ __launch_bounds__(BLOCK, 4) void gbt_eval(
    const float* __restrict__ x,        // original [BATCH][F] (XT=false path)
    const float* __restrict__ xt,       // x^T [F][BATCH]      (XT=true path)
    const int2*  __restrict__ pnodes,   // [N_TREES][64] int2, class-grouped slots
    const float* __restrict__ pleaves,  // [N_TREES][64], class-grouped slots
    const float* __restrict__ init_out, // [10]
    float*       __restrict__ out)      // [BATCH][10], written directly
{
    __shared__ float xs[N_FEATURES * SAMPLES_PB];       // 16 KB, transposed [f][s]
    __shared__ int2  nbuf[2][T_TILE * 64];              // 2 x 8 KB node tiles
    __shared__ float sums[SAMPLES_PB * SUMS_STRIDE];    // 1.4 KB

    const int tid = threadIdx.x;
    const int sample0 = blockIdx.x * SAMPLES_PB;
    const int lane    = tid & 63;
    const int wv      = tid >> 6;       // wave id 0..3 (wave-uniform)

    if (XT) {
        // DMA x^T rows straight into the transposed xs tile: per wave 4 x 1 KB.
        #pragma unroll
        for (int q = 0; q < 4; ++q) {
            int f0 = wv * 32 + q * 8;
            const char* g = (const char*)(xt
                + (size_t)(f0 + (lane >> 3)) * BATCH + sample0 + (lane & 7) * 4);
            load_lds_16(g, (char*)xs + (size_t)f0 * SAMPLES_PB * 4);
        }
    } else {
        const float4* xg = (const float4*)(x + (size_t)sample0 * N_FEATURES);
        for (int e = tid; e < SAMPLES_PB * (N_FEATURES / 4); e += BLOCK) {
            int s = e >> 5, f4 = e & 31;
            float4 v = xg[e];
            int f = f4 << 2;
            xs[(f + 0) * SAMPLES_PB + s] = v.x;
            xs[(f + 1) * SAMPLES_PB + s] = v.y;
            xs[(f + 2) * SAMPLES_PB + s] = v.z;
            xs[(f + 3) * SAMPLES_PB + s] = v.w;
        }
    }
    for (int i = tid; i < SAMPLES_PB * SUMS_STRIDE; i += BLOCK) sums[i] = 0.f;

    // Stage one 8 KB int2 node tile. Wave wv DMAs chunks 2wv,2wv+1 (trees
    // 4wv..4wv+3) -- exactly the trees its own half-waves read: wave-private.
    auto stage = [&](int tile, int b) {
        const char* g = (const char*)(pnodes + (size_t)(tile * T_TILE) * 64);
        char* lbase = (char*)&nbuf[b][0];
        #pragma unroll
        for (int q = 0; q < 2; ++q) {
            int k = wv * 2 + q;
            load_lds_16(g + k * 1024 + lane * 16, lbase + k * 1024);
        }
    };

    stage(0, 0);
    __syncthreads();   // xs is cross-wave shared: one full barrier (drains vmcnt)

    const int sLocal = tid & (SAMPLES_PB - 1);
    const int j      = tid >> 5;        // 0..7 half-wave chunks; trees 2j, 2j+1

    int cur = 0;
    for (int c = 0; c < N_CLASSES; ++c) {
        float acc = 0.f;                // 25-tile span is single-class
        for (int t25 = 0; t25 < TILES_PER_CLASS; ++t25) {
            const int tile = c * TILES_PER_CLASS + t25;
            // No __syncthreads in this loop: buffers are wave-private. Issue
            // next-tile DMA, then wait only for the OLDER pair (vmcnt FIFO).
            if (tile + 1 < N_TILES) {
                stage(tile + 1, cur ^ 1);
                __builtin_amdgcn_s_waitcnt(WAITCNT_VM2);
            } else {
                __builtin_amdgcn_s_waitcnt(WAITCNT_VM0);
            }

            const int2* nb0 = &nbuf[cur][(j * 2 + 0) * 64];
            const int2* nb1 = &nbuf[cur][(j * 2 + 1) * 64];
            int o0 = 0, o1 = 0;
            #pragma unroll
            for (int d = 0; d < DEPTH; ++d) {
                int2 a = nb0[o0];           // ds_read_b64 (interleaved f,thr)
                int2 b = nb1[o1];
                float x0 = xs[a.x * SAMPLES_PB + sLocal];
                float x1 = xs[b.x * SAMPLES_PB + sLocal];
                o0 = 2 * o0 + 1 + (x0 > __int_as_float(a.y) ? 1 : 0);
                o1 = 2 * o1 + 1 + (x1 > __int_as_float(b.y) ? 1 : 0);
            }
            const size_t slotA = (size_t)(tile * T_TILE + j * 2);
            acc += pleaves[slotA * 64       + (o0 - N_INTERNAL)];   // L2-resident;
            acc += pleaves[(slotA + 1) * 64 + (o1 - N_INTERNAL)];   // consumption
                                                                    // drains older DMAs
            cur ^= 1;
        }
        atomicAdd(&sums[sLocal * SUMS_STRIDE + c], acc);
    }
    __syncthreads();

    // Sole owner of these samples: plain coalesced stores, init folded in.
    for (int e = tid; e < SAMPLES_PB * N_CLASSES; e += BLOCK) {
        int s = e / N_CLASSES, k = e - s * N_CLASSES;
        out[(size_t)(sample0 + s) * N_CLASSES + k] =
            init_out[k] + LR * sums[s * SUMS_STRIDE + k];
    }
}

// Fallback (ws too small even for nodes+leaves): direct-global gather,
// single block per 32 samples owns all trees (no atomics on out).
__global__ __launch_bounds__(BLOCK, 8) void gbt_eval_global(
    const float* __restrict__ x,
    const int*   __restrict__ features,
    const float* __restrict__ thresholds,
    const float* __restrict__ leaf_values,
    const float* __restrict__ init_out,
    float*       __restrict__ out)
{
    __shared__ float xs[N_FEATURES * SAMPLES_PB];
    __shared__ float sums[SAMPLES_PB * N_CLASSES];
    const int tid = threadIdx.x;
    const int sample0 = blockIdx.x * SAMPLES_PB;
    {
        const float4* xg = (const float4*)(x + (size_t)sample0 * N_FEATURES);
        for (int e = tid; e < SAMPLES_PB * (N_FEATURES / 4); e += BLOCK) {
            int s = e >> 5, f4 = e & 31;
            float4 v = xg[e];
            int f = f4 << 2;
            xs[(f + 0) * SAMPLES_PB + s] = v.x;
            xs[(f + 1) * SAMPLES_PB + s] = v.y;
            xs[(f + 2) * SAMPLES_PB + s] = v.z;
            xs[(f + 3) * SAMPLES_PB + s] = v.w;
        }
    }
    for (int i = tid; i < SAMPLES_PB * N_CLASSES; i += BLOCK) sums[i] = 0.f;
    __syncthreads();
    const int sLocal = tid & (SAMPLES_PB - 1);
    const int j = tid >> 5;
    const int TPT = N_TREES / 8;        // 500 trees per half-wave chunk
    const int t0 = j * TPT;
    float acc[N_CLASSES];
    #pragma unroll
    for (int k = 0; k < N_CLASSES; ++k) acc[k] = 0.f;
    for (int i = 0; i < TPT; i += N_CLASSES) {
        const int tt = t0 + i;
        int idx[N_CLASSES];
        #pragma unroll
        for (int u = 0; u < N_CLASSES; ++u) idx[u] = 0;
        #pragma unroll
        for (int d = 0; d < DEPTH; ++d) {
            #pragma unroll
            for (int u = 0; u < N_CLASSES; ++u) {
                int base = (tt + u) * N_INTERNAL + idx[u];
                float xv = xs[features[base] * SAMPLES_PB + sLocal];
                idx[u] = 2 * idx[u] + 1 + (xv > thresholds[base] ? 1 : 0);
            }
        }
        #pragma unroll
        for (int u = 0; u < N_CLASSES; ++u)
            acc[u] += leaf_values[(size_t)(tt + u) * 64 + idx[u] - N_INTERNAL];
    }
    #pragma unroll
    for (int k = 0; k < N_CLASSES; ++k)
        atomicAdd(&sums[sLocal * N_CLASSES + k], acc[k]);
    __syncthreads();
    for (int e = tid; e < SAMPLES_PB * N_CLASSES; e += BLOCK) {
        int s = e / N_CLASSES, k = e - s * N_CLASSES;
        out[(size_t)(sample0 + s) * N_CLASSES + k] = init_out[k] + LR * sums[e];
    }
}

extern "C" void kernel_launch(void* const* d_in, const int* in_sizes, int n_in,
                              void* d_out, int out_size, void* d_ws, size_t ws_size,
                              hipStream_t stream) {
    const float* x          = (const float*)d_in[0];
    const int*   features   = (const int*)d_in[1];
    const float* thresholds = (const float*)d_in[2];
    const float* leafvals   = (const float*)d_in[3];
    const float* init_out   = (const float*)d_in[4];
    float*       out        = (float*)d_out;

    const int grid = BATCH / SAMPLES_PB;    // 1024 = 256 CU x 4 blocks

    if (ws_size >= WS_NODES_BYTES + WS_LEAVES_BYTES + WS_XT_BYTES) {
        int2*  pn = (int2*)d_ws;
        float* pl = (float*)((char*)d_ws + WS_NODES_BYTES);
        float* xt = (float*)((char*)d_ws + WS_NODES_BYTES + WS_LEAVES_BYTES);
        prep_kernel<<<XPOSE_BLOCKS + PACK_BLOCKS, BLOCK, 0, stream>>>(
            x, features, thresholds, leafvals, pn, pl, xt);
        gbt_eval<true><<<grid, BLOCK, 0, stream>>>(x, xt, pn, pl, init_out, out);
    } else if (ws_size >= WS_NODES_BYTES + WS_LEAVES_BYTES) {
        int2*  pn = (int2*)d_ws;
        float* pl = (float*)((char*)d_ws + WS_NODES_BYTES);
        int n = N_TREES * 64;
        pack_kernel<<<(n + 255) / 256, 256, 0, stream>>>(features, thresholds,
                                                         leafvals, pn, pl);
        gbt_eval<false><<<grid, BLOCK, 0, stream>>>(x, nullptr, pn, pl, init_out, out);
    } else {
        gbt_eval_global<<<grid, BLOCK, 0, stream>>>(x, features, thresholds,
                                                    leafvals, init_out, out);
    }
}

// Round 13
// 291.876 us; speedup vs baseline: 1.1908x; 1.0797x over previous
//
#include <hip/hip_runtime.h>
#include <stdint.h>

// Problem constants (from reference)
#define N_CLASSES  10
#define N_TREES    4000
#define DEPTH      6
#define N_INTERNAL 63
#define N_FEATURES 128
#define BATCH      32768
#define LR         0.1f

// Kernel config (R5/R8 skeleton; TSPLIT=1; no per-tile barriers (R12: tile
// buffers are wave-private); R13: leaf loads software-pipelined by one tile
// so their L1/L2 latency is hidden and the vmcnt FIFO never over-drains).
#define BLOCK       256
#define SAMPLES_PB  32
#define T_TILE      16                      // trees per LDS tile (8 KB int2 nodes)
#define N_TILES     (N_TREES / T_TILE)      // 250
#define TILES_PER_CLASS ((N_TREES / N_CLASSES) / T_TILE)   // 25
#define SUMS_STRIDE 11

// prep grid split
#define XPOSE_BLOCKS (BATCH / SAMPLES_PB)           // 1024
#define PACK_BLOCKS  ((N_TREES * 64) / BLOCK)       // 1000

// ws layout:
//   [0, 2.048MB)        nodes by slot, interleaved int2 (feat, thr_bits), 64/tree
//   [2.048MB, 3.072MB)  leaves (64 f32/tree), class-grouped slots
//   [3.072MB, 19.85MB)  x^T: [N_FEATURES][BATCH] f32 (DMA-friendly staging)
// slot = (t%10)*400 + t/10  (class-grouped: 25-tile runs are single-class).
#define WS_NODES_BYTES  ((size_t)N_TREES * 64 * 8)
#define WS_LEAVES_BYTES ((size_t)N_TREES * 64 * 4)
#define WS_XT_BYTES     ((size_t)N_FEATURES * BATCH * 4)

// s_waitcnt immediates (gfx9): vmcnt[3:0] | expcnt<<4 | lgkmcnt<<8
#define WAITCNT_VM4  0x0F74    // vmcnt(4): keep 4 newest (lv pair + next DMA pair)
#define WAITCNT_VM2  0x0F72    // vmcnt(2): keep 2 newest (lv pair), last tile

// Fused prep: blocks [0,1024) transpose x into x^T; blocks [1024,2024) pack
// nodes+leaves into class-grouped slots.
__global__ void prep_kernel(const float* __restrict__ x,
                            const int* __restrict__ features,
                            const float* __restrict__ thresholds,
                            const float* __restrict__ leaves,
                            int2* __restrict__ pn, float* __restrict__ pl,
                            float* __restrict__ xt) {
    const int tid = threadIdx.x;
    if (blockIdx.x < XPOSE_BLOCKS) {
        __shared__ float tile[N_FEATURES * 33];
        const int sample0 = blockIdx.x * SAMPLES_PB;
        const float4* xg = (const float4*)(x + (size_t)sample0 * N_FEATURES);
        #pragma unroll
        for (int k = 0; k < 4; ++k) {
            int e = tid + k * BLOCK;
            int s = e >> 5, f4 = e & 31;
            float4 v = xg[e];
            int f = f4 << 2;
            tile[(f + 0) * 33 + s] = v.x;
            tile[(f + 1) * 33 + s] = v.y;
            tile[(f + 2) * 33 + s] = v.z;
            tile[(f + 3) * 33 + s] = v.w;
        }
        __syncthreads();
        #pragma unroll
        for (int k = 0; k < 4; ++k) {
            int e = tid + k * BLOCK;
            int f = e >> 3, sq = e & 7;
            float4 w;
            w.x = tile[f * 33 + 4 * sq + 0];
            w.y = tile[f * 33 + 4 * sq + 1];
            w.z = tile[f * 33 + 4 * sq + 2];
            w.w = tile[f * 33 + 4 * sq + 3];
            *(float4*)(xt + (size_t)f * BATCH + sample0 + 4 * sq) = w;
        }
    } else {
        int i = (blockIdx.x - XPOSE_BLOCKS) * BLOCK + tid;
        int t = i >> 6, n = i & 63;
        int slot = (t % N_CLASSES) * (N_TREES / N_CLASSES) + (t / N_CLASSES);
        if (n < N_INTERNAL)
            pn[slot * 64 + n] = make_int2(features[t * N_INTERNAL + n],
                                          __float_as_int(thresholds[t * N_INTERNAL + n]));
        pl[slot * 64 + n] = leaves[t * 64 + n];
    }
}

// Standalone pack (mid tier without xt space)
__global__ void pack_kernel(const int* __restrict__ features,
                            const float* __restrict__ thresholds,
                            const float* __restrict__ leaves,
                            int2* __restrict__ pn, float* __restrict__ pl) {
    int i = blockIdx.x * blockDim.x + threadIdx.x;
    int t = i >> 6, n = i & 63;
    if (t < N_TREES) {
        int slot = (t % N_CLASSES) * (N_TREES / N_CLASSES) + (t / N_CLASSES);
        if (n < N_INTERNAL)
            pn[slot * 64 + n] = make_int2(features[t * N_INTERNAL + n],
                                          __float_as_int(thresholds[t * N_INTERNAL + n]));
        pl[slot * 64 + n] = leaves[t * 64 + n];
    }
}

// CK-style addrspace casts for global_load_lds (proven R5..R12).
__device__ __forceinline__ void load_lds_16(const void* g, void* l) {
    const auto* g1 = reinterpret_cast<const __attribute__((address_space(1))) uint32_t*>(
        reinterpret_cast<uintptr_t>(g));
    auto* l3 = reinterpret_cast<__attribute__((address_space(3))) uint32_t*>(
        reinterpret_cast<uintptr_t>(l));
    __builtin_amdgcn_global_load_lds(g1, l3, 16, 0, 0);
}

template <bool XT>
__global__ __launch_bounds__(BLOCK, 4) void gbt_eval(
    const float* __restrict__ x,        // original [BATCH][F] (XT=false path)
    const float* __restrict__ xt,       // x^T [F][BATCH]      (XT=true path)
    const int2*  __restrict__ pnodes,   // [N_TREES][64] int2, class-grouped slots
    const float* __restrict__ pleaves,  // [N_TREES][64], class-grouped slots
    const float* __restrict__ init_out, // [10]
    float*       __restrict__ out)      // [BATCH][10], written directly
{
    __shared__ float xs[N_FEATURES * SAMPLES_PB];       // 16 KB, transposed [f][s]
    __shared__ int2  nbuf[2][T_TILE * 64];              // 2 x 8 KB node tiles
    __shared__ float sums[SAMPLES_PB * SUMS_STRIDE];    // 1.4 KB

    const int tid = threadIdx.x;
    const int sample0 = blockIdx.x * SAMPLES_PB;
    const int lane    = tid & 63;
    const int wv      = tid >> 6;       // wave id 0..3 (wave-uniform)

    if (XT) {
        #pragma unroll
        for (int q = 0; q < 4; ++q) {
            int f0 = wv * 32 + q * 8;
            const char* g = (const char*)(xt
                + (size_t)(f0 + (lane >> 3)) * BATCH + sample0 + (lane & 7) * 4);
            load_lds_16(g, (char*)xs + (size_t)f0 * SAMPLES_PB * 4);
        }
    } else {
        const float4* xg = (const float4*)(x + (size_t)sample0 * N_FEATURES);
        for (int e = tid; e < SAMPLES_PB * (N_FEATURES / 4); e += BLOCK) {
            int s = e >> 5, f4 = e & 31;
            float4 v = xg[e];
            int f = f4 << 2;
            xs[(f + 0) * SAMPLES_PB + s] = v.x;
            xs[(f + 1) * SAMPLES_PB + s] = v.y;
            xs[(f + 2) * SAMPLES_PB + s] = v.z;
            xs[(f + 3) * SAMPLES_PB + s] = v.w;
        }
    }
    for (int i = tid; i < SAMPLES_PB * SUMS_STRIDE; i += BLOCK) sums[i] = 0.f;

    // Stage one 8 KB int2 node tile. Wave wv DMAs chunks 2wv,2wv+1 (trees
    // 4wv..4wv+3) -- exactly the trees its own half-waves read: wave-private.
    auto stage = [&](int tile, int b) {
        const char* g = (const char*)(pnodes + (size_t)(tile * T_TILE) * 64);
        char* lbase = (char*)&nbuf[b][0];
        #pragma unroll
        for (int q = 0; q < 2; ++q) {
            int k = wv * 2 + q;
            load_lds_16(g + k * 1024 + lane * 16, lbase + k * 1024);
        }
    };

    stage(0, 0);
    __syncthreads();   // xs is cross-wave shared: one full barrier (drains vmcnt)

    const int sLocal = tid & (SAMPLES_PB - 1);
    const int j      = tid >> 5;        // 0..7 half-wave chunks; trees 2j, 2j+1

    int cur = 0;
    for (int c = 0; c < N_CLASSES; ++c) {
        float acc = 0.f;
        float lv0 = 0.f, lv1 = 0.f;     // previous tile's leaf loads (pipelined)
        for (int t25 = 0; t25 < TILES_PER_CLASS; ++t25) {
            const int tile = c * TILES_PER_CLASS + t25;
            // Issue next-tile DMA, then wait for THIS tile's DMA only:
            // vmcnt(4) keeps {lv pair, next DMA pair} in flight (FIFO order:
            // DMA(t) < lv(t-1) < DMA(t+1)).
            if (tile + 1 < N_TILES) {
                stage(tile + 1, cur ^ 1);
                __builtin_amdgcn_s_waitcnt(WAITCNT_VM4);
            } else {
                __builtin_amdgcn_s_waitcnt(WAITCNT_VM2);
            }

            const int2* nb0 = &nbuf[cur][(j * 2 + 0) * 64];
            const int2* nb1 = &nbuf[cur][(j * 2 + 1) * 64];
            int o0 = 0, o1 = 0;
            #pragma unroll
            for (int d = 0; d < DEPTH; ++d) {
                int2 a = nb0[o0];           // ds_read_b64 (interleaved f,thr)
                int2 b = nb1[o1];
                float x0 = xs[a.x * SAMPLES_PB + sLocal];
                float x1 = xs[b.x * SAMPLES_PB + sLocal];
                o0 = 2 * o0 + 1 + (x0 > __int_as_float(a.y) ? 1 : 0);
                o1 = 2 * o1 + 1 + (x1 > __int_as_float(b.y) ? 1 : 0);
            }
            const size_t slotA = (size_t)(tile * T_TILE + j * 2);
            // Consume PREVIOUS tile's leaves (issued one iteration ago ->
            // latency hidden; they're older than DMA(t+1), so this wait does
            // not drain the prefetch), then issue this tile's leaf loads.
            acc += lv0 + lv1;
            lv0 = pleaves[slotA * 64       + (o0 - N_INTERNAL)];
            lv1 = pleaves[(slotA + 1) * 64 + (o1 - N_INTERNAL)];
            cur ^= 1;
        }
        acc += lv0 + lv1;               // flush the class's final pair
        atomicAdd(&sums[sLocal * SUMS_STRIDE + c], acc);
    }
    __syncthreads();

    // Sole owner of these samples: plain coalesced stores, init folded in.
    for (int e = tid; e < SAMPLES_PB * N_CLASSES; e += BLOCK) {
        int s = e / N_CLASSES, k = e - s * N_CLASSES;
        out[(size_t)(sample0 + s) * N_CLASSES + k] =
            init_out[k] + LR * sums[s * SUMS_STRIDE + k];
    }
}

// Fallback (ws too small even for nodes+leaves): direct-global gather,
// single block per 32 samples owns all trees (no atomics on out).
__global__ __launch_bounds__(BLOCK, 8) void gbt_eval_global(
    const float* __restrict__ x,
    const int*   __restrict__ features,
    const float* __restrict__ thresholds,
    const float* __restrict__ leaf_values,
    const float* __restrict__ init_out,
    float*       __restrict__ out)
{
    __shared__ float xs[N_FEATURES * SAMPLES_PB];
    __shared__ float sums[SAMPLES_PB * N_CLASSES];
    const int tid = threadIdx.x;
    const int sample0 = blockIdx.x * SAMPLES_PB;
    {
        const float4* xg = (const float4*)(x + (size_t)sample0 * N_FEATURES);
        for (int e = tid; e < SAMPLES_PB * (N_FEATURES / 4); e += BLOCK) {
            int s = e >> 5, f4 = e & 31;
            float4 v = xg[e];
            int f = f4 << 2;
            xs[(f + 0) * SAMPLES_PB + s] = v.x;
            xs[(f + 1) * SAMPLES_PB + s] = v.y;
            xs[(f + 2) * SAMPLES_PB + s] = v.z;
            xs[(f + 3) * SAMPLES_PB + s] = v.w;
        }
    }
    for (int i = tid; i < SAMPLES_PB * N_CLASSES; i += BLOCK) sums[i] = 0.f;
    __syncthreads();
    const int sLocal = tid & (SAMPLES_PB - 1);
    const int j = tid >> 5;
    const int TPT = N_TREES / 8;
    const int t0 = j * TPT;
    float acc[N_CLASSES];
    #pragma unroll
    for (int k = 0; k < N_CLASSES; ++k) acc[k] = 0.f;
    for (int i = 0; i < TPT; i += N_CLASSES) {
        const int tt = t0 + i;
        int idx[N_CLASSES];
        #pragma unroll
        for (int u = 0; u < N_CLASSES; ++u) idx[u] = 0;
        #pragma unroll
        for (int d = 0; d < DEPTH; ++d) {
            #pragma unroll
            for (int u = 0; u < N_CLASSES; ++u) {
                int base = (tt + u) * N_INTERNAL + idx[u];
                float xv = xs[features[base] * SAMPLES_PB + sLocal];
                idx[u] = 2 * idx[u] + 1 + (xv > thresholds[base] ? 1 : 0);
            }
        }
        #pragma unroll
        for (int u = 0; u < N_CLASSES; ++u)
            acc[u] += leaf_values[(size_t)(tt + u) * 64 + idx[u] - N_INTERNAL];
    }
    #pragma unroll
    for (int k = 0; k < N_CLASSES; ++k)
        atomicAdd(&sums[sLocal * N_CLASSES + k], acc[k]);
    __syncthreads();
    for (int e = tid; e < SAMPLES_PB * N_CLASSES; e += BLOCK) {
        int s = e / N_CLASSES, k = e - s * N_CLASSES;
        out[(size_t)(sample0 + s) * N_CLASSES + k] = init_out[k] + LR * sums[e];
    }
}

extern "C" void kernel_launch(void* const* d_in, const int* in_sizes, int n_in,
                              void* d_out, int out_size, void* d_ws, size_t ws_size,
                              hipStream_t stream) {
    const float* x          = (const float*)d_in[0];
    const int*   features   = (const int*)d_in[1];
    const float* thresholds = (const float*)d_in[2];
    const float* leafvals   = (const float*)d_in[3];
    const float* init_out   = (const float*)d_in[4];
    float*       out        = (float*)d_out;

    const int grid = BATCH / SAMPLES_PB;    // 1024 = 256 CU x 4 blocks

    if (ws_size >= WS_NODES_BYTES + WS_LEAVES_BYTES + WS_XT_BYTES) {
        int2*  pn = (int2*)d_ws;
        float* pl = (float*)((char*)d_ws + WS_NODES_BYTES);
        float* xt = (float*)((char*)d_ws + WS_NODES_BYTES + WS_LEAVES_BYTES);
        prep_kernel<<<XPOSE_BLOCKS + PACK_BLOCKS, BLOCK, 0, stream>>>(
            x, features, thresholds, leafvals, pn, pl, xt);
        gbt_eval<true><<<grid, BLOCK, 0, stream>>>(x, xt, pn, pl, init_out, out);
    } else if (ws_size >= WS_NODES_BYTES + WS_LEAVES_BYTES) {
        int2*  pn = (int2*)d_ws;
        float* pl = (float*)((char*)d_ws + WS_NODES_BYTES);
        int n = N_TREES * 64;
        pack_kernel<<<(n + 255) / 256, 256, 0, stream>>>(features, thresholds,
                                                         leafvals, pn, pl);
        gbt_eval<false><<<grid, BLOCK, 0, stream>>>(x, nullptr, pn, pl, init_out, out);
    } else {
        gbt_eval_global<<<grid, BLOCK, 0, stream>>>(x, features, thresholds,
                                                    leafvals, init_out, out);
    }
}